// Round 2
// baseline (8670.757 us; speedup 1.0000x reference)
//
#include <hip/hip_runtime.h>
#include <hip/hip_bf16.h>

// sLSTM persistent-kernel design (R2: bf16 -> fp16 for 8x lower quant noise):
//  - 64 workgroups (256 thr = 4 waves), WG w owns h-cols [8w, 8w+8) for all 64 batches.
//  - Weights live in LDS as fp16 for the whole kernel (58.6 KB/WG).
//  - One device-wide flag barrier per timestep; h broadcast through uncached
//    agent-scope atomics (no cross-XCD staleness possible).
//  - MFMA f32_16x16x32_f16; gate tiles packed [i|g],[f|o]; shfl_xor(8) combine.
//  - Wf-GEMM(t) and W_hh-GEMM(t+1) merged over the same h_t A-fragments.
//  - x-projection(t+1) overlapped with barrier wait.
//  R1 evidence: outputs 0,1 (out, h) PASSED with bf16 -> algorithm + sync correct;
//  output 2 (c) failed 3.9e-2 vs 1.945e-2 -> multiplicative exp-gate error chain,
//  fixed by fp16 operands (quant error 2^-11 vs 2^-8).

#define TB 1024
#define BB 64
#define HH 512
#define II 128
#define NWG 64

typedef __attribute__((ext_vector_type(8))) _Float16 f16x8;
typedef __attribute__((ext_vector_type(4))) float f32x4;

__device__ __forceinline__ unsigned short f2h(float v){
    _Float16 h = (_Float16)v;
    return __builtin_bit_cast(unsigned short, h);
}
__device__ __forceinline__ float sigm(float x){ return 1.0f/(1.0f + __expf(-x)); }
// tanh via 1 - 2/(e^{2x}+1): no inf/inf NaN at large |x|
__device__ __forceinline__ float tanh1(float x){ float e = __expf(2.0f*x); return 1.0f - 2.0f/(e+1.0f); }

// x [B][T][I] fp32  ->  xh [T][B][I] fp16
__global__ __launch_bounds__(256) void convert_x_kernel(const float* __restrict__ x,
                                                        unsigned short* __restrict__ xh){
    int idx = (blockIdx.x*256 + threadIdx.x) * 4;   // element idx in out layout
    int i  = idx & 127;
    int tb = idx >> 7;
    int b  = tb & 63;
    int t  = tb >> 6;
    const float4 v = *(const float4*)(x + ((size_t)((b << 10) + t))*128 + i);
    unsigned long long pack =  (unsigned long long)f2h(v.x)
                            | ((unsigned long long)f2h(v.y) << 16)
                            | ((unsigned long long)f2h(v.z) << 32)
                            | ((unsigned long long)f2h(v.w) << 48);
    *(unsigned long long*)(xh + idx) = pack;
}

__global__ __launch_bounds__(256) void slstm_kernel(
    const float* __restrict__ W_ih, const float* __restrict__ W_hh,
    const float* __restrict__ b_ih, const float* __restrict__ b_hh,
    const float* __restrict__ Wf,  const float* __restrict__ bfv,
    const unsigned short* __restrict__ xh,   // [T][B][I] fp16
    unsigned short* hbuf,                    // 2 * [B][H] fp16 (double buffer)
    unsigned int* flags,                     // [NWG]
    float* __restrict__ out)
{
    const int tid   = threadIdx.x;
    const int wg    = blockIdx.x;        // 0..63
    const int wave  = tid >> 6;          // 0..3  -> batch tile
    const int lane  = tid & 63;
    const int q     = lane >> 4;         // quad 0..3
    const int cc    = lane & 15;         // tile column
    const int b0    = wave << 4;         // batch base
    const int jbase = wg << 3;           // owned h-col base

    // LDS weight slices (fp16, padded stride 520 -> 2-way bank aliasing, free)
    __shared__ unsigned short whh[32*520];   // rows: 0-7 i, 8-15 g, 16-23 f, 24-31 o
    __shared__ unsigned short wih[32*136];   // same gate packing, K=128
    __shared__ unsigned short wfl[16*520];   // rows 0-7 Wf, 8-15 zeros

    for (int idx = tid; idx < 32*512; idx += 256){
        int r = idx >> 9, k = idx & 511;
        int ti = r >> 4, half = (r >> 3) & 1, c8 = r & 7;
        int gate = (ti == 0) ? (half ? 2 : 0) : (half ? 3 : 1);  // i,g | f,o
        whh[r*520 + k] = f2h(W_hh[(size_t)(gate*512 + jbase + c8)*512 + k]);
    }
    for (int idx = tid; idx < 32*128; idx += 256){
        int r = idx >> 7, k = idx & 127;
        int ti = r >> 4, half = (r >> 3) & 1, c8 = r & 7;
        int gate = (ti == 0) ? (half ? 2 : 0) : (half ? 3 : 1);
        wih[r*136 + k] = f2h(W_ih[(size_t)(gate*512 + jbase + c8)*128 + k]);
    }
    for (int idx = tid; idx < 16*512; idx += 256){
        int r = idx >> 9, k = idx & 511;
        wfl[r*520 + k] = (r < 8) ? f2h(Wf[(size_t)(jbase + r)*512 + k]) : (unsigned short)0;
    }
    __syncthreads();

    const int j8 = cc & 7;
    const int j  = jbase + j8;
    const float bi_i = b_ih[j]        + b_hh[j];
    const float bi_f = b_ih[512 + j]  + b_hh[512 + j];
    const float bi_g = b_ih[1024 + j] + b_hh[1024 + j];
    const float bi_o = b_ih[1536 + j] + b_hh[1536 + j];
    const float bfb  = bfv[j];
    const bool valid  = (cc < 8);
    const bool vstore = valid && ((cc & 1) == 0);

    f32x4 accA, accB, accnA, accnB, accF;
    #pragma unroll
    for (int r = 0; r < 4; ++r){ accA[r] = 0.f; accB[r] = 0.f; }
    float creg[4] = {0.f, 0.f, 0.f, 0.f};
    float hreg[4] = {0.f, 0.f, 0.f, 0.f};

    auto xproj = [&](int t, f32x4& dA, f32x4& dB){
        const unsigned short* xrow = xh + (size_t)((t << 6) + b0 + cc) * 128 + (q << 3);
        #pragma unroll
        for (int k0 = 0; k0 < 128; k0 += 32){
            f16x8 a  = *(const f16x8*)(xrow + k0);
            f16x8 w1 = *(const f16x8*)(&wih[cc*136 + k0 + (q<<3)]);
            f16x8 w2 = *(const f16x8*)(&wih[(16+cc)*136 + k0 + (q<<3)]);
            dA = __builtin_amdgcn_mfma_f32_16x16x32_f16(a, w1, dA, 0, 0, 0);
            dB = __builtin_amdgcn_mfma_f32_16x16x32_f16(a, w2, dB, 0, 0, 0);
        }
    };

    xproj(0, accA, accB);   // gates(t=0) = x-projection only (h0 = 0)

    for (int t = 0; t < TB; ++t){
        // ---- gate combine + activations ----
        float c1[4];
        #pragma unroll
        for (int r = 0; r < 4; ++r){
            float sA = __shfl_xor(accA[r], 8, 64);   // low lanes receive g
            float sB = __shfl_xor(accB[r], 8, 64);   // low lanes receive o
            float vi = sigm(accA[r] + bi_i);
            float vg = tanh1(sA + bi_g);
            float vf = sigm(accB[r] + bi_f);
            float vo = sigm(sB + bi_o);
            c1[r]   = vf * creg[r] + vi * vg;
            hreg[r] = vo * tanh1(c1[r]);
        }
        // ---- publish h_t slice (uncached agent atomics, packed pairs) ----
        unsigned short* hw = hbuf + (t & 1) * (BB*HH);
        #pragma unroll
        for (int r = 0; r < 4; ++r){
            float hp = __shfl_xor(hreg[r], 1, 64);
            if (vstore){
                int b = b0 + (q << 2) + r;
                unsigned int pack = (unsigned)f2h(hreg[r]) | ((unsigned)f2h(hp) << 16);
                __hip_atomic_store((unsigned int*)(hw + b*HH + j), pack,
                                   __ATOMIC_RELAXED, __HIP_MEMORY_SCOPE_AGENT);
            }
        }
        __syncthreads();   // HIP barrier drains vmcnt(0): all waves' h stores are globally visible
        if (tid == 0)
            __hip_atomic_store(&flags[wg], (unsigned)(t + 1),
                               __ATOMIC_RELEASE, __HIP_MEMORY_SCOPE_AGENT);

        // ---- out stores (no cross-WG ordering needed) ----
        if (valid){
            #pragma unroll
            for (int r = 0; r < 4; ++r){
                int b = b0 + (q << 2) + r;
                __builtin_nontemporal_store(hreg[r], out + (size_t)b*(TB*HH) + (size_t)t*HH + j);
            }
        }

        // ---- overlap barrier latency with x-projection of t+1 ----
        #pragma unroll
        for (int r = 0; r < 4; ++r){ accnA[r] = 0.f; accnB[r] = 0.f; }
        if (t + 1 < TB) xproj(t + 1, accnA, accnB);

        // ---- barrier wait: all 64 flags >= t+1 (one wave-wide load per poll) ----
        if (tid < 64){
            while (true){
                unsigned v = __hip_atomic_load(&flags[lane],
                                __ATOMIC_ACQUIRE, __HIP_MEMORY_SCOPE_AGENT);
                if (__ballot(v >= (unsigned)(t + 1)) == ~0ull) break;
            }
        }
        __syncthreads();

        // ---- merged: Wf-GEMM(t) + recurrent GEMM(t+1) over the same h_t frags ----
        #pragma unroll
        for (int r = 0; r < 4; ++r) accF[r] = 0.f;
        unsigned short* hr = hbuf + (t & 1) * (BB*HH);
        unsigned long long* hrow = (unsigned long long*)(hr + (b0 + cc)*HH + (q << 3));
        const bool more = (t + 1 < TB);
        #pragma unroll
        for (int k0 = 0; k0 < 512; k0 += 32){
            unsigned long long l0 = __hip_atomic_load(hrow + (k0 >> 2),
                                        __ATOMIC_RELAXED, __HIP_MEMORY_SCOPE_AGENT);
            unsigned long long l1 = __hip_atomic_load(hrow + (k0 >> 2) + 1,
                                        __ATOMIC_RELAXED, __HIP_MEMORY_SCOPE_AGENT);
            union { unsigned long long u[2]; f16x8 v; } uu;
            uu.u[0] = l0; uu.u[1] = l1;
            f16x8 a   = uu.v;
            f16x8 wf8 = *(const f16x8*)(&wfl[cc*520 + k0 + (q<<3)]);
            accF = __builtin_amdgcn_mfma_f32_16x16x32_f16(a, wf8, accF, 0, 0, 0);
            if (more){
                f16x8 w1 = *(const f16x8*)(&whh[cc*520 + k0 + (q<<3)]);
                f16x8 w2 = *(const f16x8*)(&whh[(16+cc)*520 + k0 + (q<<3)]);
                accnA = __builtin_amdgcn_mfma_f32_16x16x32_f16(a, w1, accnA, 0, 0, 0);
                accnB = __builtin_amdgcn_mfma_f32_16x16x32_f16(a, w2, accnB, 0, 0, 0);
            }
        }
        // exponential forget gate: c = exp(h@Wf^T + bf) * c'
        #pragma unroll
        for (int r = 0; r < 4; ++r){
            float fe = __expf(accF[r] + bfb);
            creg[r] = fe * c1[r];
        }
        accA = accnA; accB = accnB;
    }

    // final h, c
    if (valid){
        #pragma unroll
        for (int r = 0; r < 4; ++r){
            int b = b0 + (q << 2) + r;
            out[(size_t)(BB)*TB*HH + (size_t)b*HH + j] = hreg[r];
            out[(size_t)(BB)*TB*HH + (size_t)BB*HH + (size_t)b*HH + j] = creg[r];
        }
    }
}

extern "C" void kernel_launch(void* const* d_in, const int* in_sizes, int n_in,
                              void* d_out, int out_size, void* d_ws, size_t ws_size,
                              hipStream_t stream) {
    const float* x    = (const float*)d_in[0];
    const float* W_ih = (const float*)d_in[1];
    const float* W_hh = (const float*)d_in[2];
    const float* b_ih = (const float*)d_in[3];
    const float* b_hh = (const float*)d_in[4];
    const float* Wf   = (const float*)d_in[5];
    const float* bfv  = (const float*)d_in[6];
    // d_in[7], d_in[8] (Wi, bi) unused by the reference computation.

    // workspace layout: [flags 256B][hbuf 2*64*512*2B][xh 16 MiB]
    unsigned int*   flags = (unsigned int*)d_ws;
    unsigned short* hbuf  = (unsigned short*)((char*)d_ws + 256);
    unsigned short* xh    = (unsigned short*)((char*)d_ws + 256 + 2*BB*HH*2);
    float* out = (float*)d_out;

    hipMemsetAsync(flags, 0, 256, stream);
    convert_x_kernel<<<(BB*TB*II/4)/256, 256, 0, stream>>>(x, xh);
    slstm_kernel<<<NWG, 256, 0, stream>>>(W_ih, W_hh, b_ih, b_hh, Wf, bfv,
                                          xh, hbuf, flags, out);
}